// Round 2
// baseline (131.752 us; speedup 1.0000x reference)
//
#include <hip/hip_runtime.h>
#include <hip/hip_bf16.h>

typedef __attribute__((ext_vector_type(8))) short bf16x8;
typedef __attribute__((ext_vector_type(4))) float f32x4;

#define B_ 2048
#define S_ 200
#define D_ 128
#define H_ 64
#define SP 208  /* S padded to 13*16 */

__device__ __forceinline__ unsigned short f2bf(float f) {
    union { float f; unsigned u; } v; v.f = f;
    unsigned r = v.u + 0x7fffu + ((v.u >> 16) & 1u);   // RNE
    return (unsigned short)(r >> 16);
}

// LDS X layout: 32 k-groups (g: 0..15 = h, 16..31 = t*h) x 64 rows x 16B chunks.
// XOR swizzle spreads banks for both the staging writes and the MFMA A reads.
__device__ __forceinline__ int xoff(int g, int r) {
    return (((g << 6) + r) << 4) ^ ((g & 7) << 4);
}

__global__ __launch_bounds__(256)
void din_kernel(const float* __restrict__ tgt,
                const float* __restrict__ hist,
                const int*   __restrict__ mask,
                const float* __restrict__ W1,
                const float* __restrict__ b1,
                const float* __restrict__ W2,
                const float* __restrict__ b2,
                float* __restrict__ out)
{
    __shared__ __align__(16) char Xb[32768];
    __shared__ float t_lds[128];
    __shared__ float logits[SP];
    __shared__ float partial[4][SP];
    __shared__ float red[8];
    __shared__ float osum[128];

    const int tid  = threadIdx.x;
    const int b    = blockIdx.x;
    const int lane = tid & 63;
    const int wv   = tid >> 6;
    const int n    = (wv << 4) + (lane & 15);   // this wave's output column 0..63
    const int kq   = (lane >> 4) << 3;          // k sub-offset within 32-wide K step

    // stage target row t[b][0..127]
    if (tid < 32) {
        float4 tv = ((const float4*)(tgt + (size_t)b * D_))[tid];
        *(float4*)&t_lds[tid * 4] = tv;
    }
    __syncthreads();

    // Build B fragments, folding W1 on the fly:
    //   W'[k][n] = (k<128) ? W1b[k][n]-W1c[k][n] : W1d[k-128][n]
    // B frag layout (16x16x32): lane holds col n=lane&15, k = ks*32 + (lane>>4)*8 + e
    bf16x8 bfrag[8];
    #pragma unroll
    for (int ks = 0; ks < 8; ++ks) {
        bf16x8 tmp;
        #pragma unroll
        for (int e = 0; e < 8; ++e) {
            int k = ks * 32 + kq + e;
            float f;
            if (k < 128) f = W1[(128 + k) * H_ + n] - W1[(256 + k) * H_ + n];
            else         f = W1[(256 + k) * H_ + n];   // row 384+(k-128) == 256+k
            tmp[e] = (short)f2bf(f);
        }
        bfrag[ks] = tmp;
    }

    // Exact fp32 per-batch term: tA[n] = sum_d t[d]*(W1a[d][n]+W1c[d][n]) + b1[n]
    float ta = 0.f;
    {
        int dbase = (lane >> 4) << 5;
        #pragma unroll 8
        for (int d = dbase; d < dbase + 32; ++d)
            ta += t_lds[d] * (W1[d * H_ + n] + W1[(256 + d) * H_ + n]);
        ta += __shfl_xor(ta, 16);
        ta += __shfl_xor(ta, 32);
        ta += b1[n];
    }
    const float w2n = W2[n];

    // ---- pass 1: logits via MFMA over 64-row chunks ----
    for (int base = 0; base < SP; base += 64) {
        const int nrows = (SP - base) < 64 ? (SP - base) : 64;
        __syncthreads();   // previous chunk's MFMA reads done before overwrite
        for (int idx = tid; idx < nrows * 32; idx += 256) {
            int r = idx >> 5, q = idx & 31;
            int s = base + r;
            float4 hv = make_float4(0.f, 0.f, 0.f, 0.f);
            if (s < S_) hv = *(const float4*)(hist + ((size_t)b * S_ + s) * D_ + q * 4);
            float4 tv = *(const float4*)&t_lds[q * 4];
            ushort4 hh, th;
            hh.x = f2bf(hv.x);        hh.y = f2bf(hv.y);
            hh.z = f2bf(hv.z);        hh.w = f2bf(hv.w);
            th.x = f2bf(hv.x * tv.x); th.y = f2bf(hv.y * tv.y);
            th.z = f2bf(hv.z * tv.z); th.w = f2bf(hv.w * tv.w);
            int g = q >> 1, sub = (q & 1) << 3;
            *(ushort4*)(Xb + xoff(g,      r) + sub) = hh;
            *(ushort4*)(Xb + xoff(g + 16, r) + sub) = th;
        }
        __syncthreads();
        const int nmt = nrows >> 4;
        for (int mt = 0; mt < nmt; ++mt) {
            f32x4 acc = {0.f, 0.f, 0.f, 0.f};
            int r = (mt << 4) + (lane & 15);   // A row within chunk
            #pragma unroll
            for (int ks = 0; ks < 8; ++ks) {
                int gg = (ks << 2) + (lane >> 4);
                bf16x8 a = *(const bf16x8*)(Xb + xoff(gg, r));
                acc = __builtin_amdgcn_mfma_f32_16x16x32_bf16(a, bfrag[ks], acc, 0, 0, 0);
            }
            // D layout: col = lane&15 (our n), row = (lane>>4)*4 + e
            #pragma unroll
            for (int e = 0; e < 4; ++e) {
                float hid = acc[e] + ta;
                float vv  = fmaxf(hid, 0.f) * w2n;
                vv += __shfl_xor(vv, 1);
                vv += __shfl_xor(vv, 2);
                vv += __shfl_xor(vv, 4);
                vv += __shfl_xor(vv, 8);
                if ((lane & 15) == 0)
                    partial[wv][base + (mt << 4) + ((lane >> 4) << 2) + e] = vv;
            }
        }
    }
    __syncthreads();

    // combine wave partials + mask (w*m + (-1e9)*(1-m) == m ? w : -1e9)
    if (tid < SP) {
        float lg = partial[0][tid] + partial[1][tid] + partial[2][tid]
                 + partial[3][tid] + b2[0];
        int m = (tid < S_) ? mask[(size_t)b * S_ + tid] : 0;
        logits[tid] = m ? lg : -1e9f;
    }
    __syncthreads();

    // ---- softmax over SP values ----
    {
        float v = (tid < SP) ? logits[tid] : -1e30f;
        #pragma unroll
        for (int m = 1; m < 64; m <<= 1) v = fmaxf(v, __shfl_xor(v, m));
        if (lane == 0) red[wv] = v;
        __syncthreads();
        float mx = fmaxf(fmaxf(red[0], red[1]), fmaxf(red[2], red[3]));
        float p = (tid < SP) ? expf(logits[tid] - mx) : 0.f;
        float sv = p;
        #pragma unroll
        for (int m = 1; m < 64; m <<= 1) sv += __shfl_xor(sv, m);
        if (lane == 0) red[4 + wv] = sv;
        __syncthreads();
        float denom = red[4] + red[5] + red[6] + red[7];
        if (tid < SP) logits[tid] = p / denom;
    }
    __syncthreads();

    // ---- pass 2: out[b][d] = sum_s w[s]*hist[b][s][d], fp32 from global ----
    {
        int d    = tid & 127;
        int half = tid >> 7;
        const float* hp = hist + (size_t)b * S_ * D_ + (size_t)half * 100 * D_ + d;
        float acc = 0.f;
        #pragma unroll 4
        for (int s = 0; s < 100; ++s)
            acc = fmaf(logits[half * 100 + s], hp[(size_t)s * D_], acc);
        if (half == 0) osum[d] = acc;
        __syncthreads();
        if (half == 1) out[(size_t)b * D_ + d] = osum[d] + acc;
    }
}

extern "C" void kernel_launch(void* const* d_in, const int* in_sizes, int n_in,
                              void* d_out, int out_size, void* d_ws, size_t ws_size,
                              hipStream_t stream) {
    const float* tgt  = (const float*)d_in[0];
    const float* hist = (const float*)d_in[1];
    const int*   mask = (const int*)d_in[2];
    const float* W1   = (const float*)d_in[3];
    const float* b1   = (const float*)d_in[4];
    const float* W2   = (const float*)d_in[5];
    const float* b2   = (const float*)d_in[6];
    float* out = (float*)d_out;
    din_kernel<<<B_, 256, 0, stream>>>(tgt, hist, mask, W1, b1, W2, b2, out);
}